// Round 20
// baseline (516.727 us; speedup 1.0000x reference)
//
#include <hip/hip_runtime.h>
#include <math.h>
#include <stdint.h>

// B=16, XL=YL=2048, D=1024. fp16 1-pass pipeline + mask compaction, uniform
// NYMAX padding (round-20: broadcast max_z NYPAD so all z share one T):
//   build_idx: compact unmasked y col indices; NY (per-z), NYPAD (ceil128)
//   reduce_ny: NYPAD[z] <- max_z NYPAD (uniform T; per-z NY kept for -inf)
//   cvt_f16  : x -> fp16 rows [0,2048)
//   gather_y : yc rows fp16 (rows [2048,2048+NYMAX), pad rows zero) + yT fp16
//   proj     : p = relu([x;yc]16 @ W16^T + b) -> pHi fp16   (gemmw EPI1)
//   score    : sc = xp @ ypc^T, col>=NY -> -inf -> fp32     (gemmw EPI2)
//   soft     : w = softmax over NYMAX cols -> fp16 (pad cols exactly 0)
//   out      : out = w @ yT^T, K=NYMAX -> fp32              (gemmw EPI0)
// Pad-correctness: pad p rows = relu(bias) but scores epilogue -inf's col>=NY
// (per-z NY); softmax then zeroes those w cols; yT pad cols are zero. Exact.
// gemmw (R17/R19-verified best): 128x256 tile, 4 waves (wave 64x128, acc 4x8),
// BK=32, TRIPLE-buffered LDS (3x24KB=72KB, launch_bounds(256,2) -> 2 blocks/CU;
// (256,3) spills the 128-VGPR accumulator — R18: WRITE_SIZE 1.5GB, 3.5x slower).
// Counted vmcnt never drains mid-loop: stage(t+2) then vmcnt(12) keeps 2 tiles
// in flight across both barriers. setprio(1) around MFMA cluster. Pair-row XOR
// swizzle (measured 0-conflict) + XCD-bijective block swizzle.

typedef __attribute__((ext_vector_type(8))) _Float16 f16x8;
typedef __attribute__((ext_vector_type(4))) float f32x4;

__device__ __forceinline__ ushort h2u(_Float16 h) { return __builtin_bit_cast(ushort, h); }

__device__ __forceinline__ void ld16(const ushort* g, ushort* l) {
    __builtin_amdgcn_global_load_lds(
        (__attribute__((address_space(1))) void*)(g),
        (__attribute__((address_space(3))) void*)(l), 16, 0, 0);
}

#define BAR()   { __builtin_amdgcn_s_barrier(); asm volatile("" ::: "memory"); }
#define VMW(N)  asm volatile("s_waitcnt vmcnt(" #N ")" ::: "memory");

// C = A @ B^T; A,B fp16 k-contiguous. Tile 128(M) x 256(N), BK=32, K = T*32.
// MODE 1: proj (A-row early exit >= 2048+NYPAD). MODE 2: scores (B-col exit
// >= NYPAD; col>=NY -> -inf). MODE 3: out (T = NYPAD/32, uniform across z).
// EPI 0: fp32 C. EPI 1: relu(C+bias[n]) -> fp16 Chi. EPI 2: -inf mask, fp32.
template<int EPI, int MODE>
__global__ __launch_bounds__(256, 2) void gemmw(
    const ushort* __restrict__ A, size_t zsA,
    const ushort* __restrict__ B, size_t zsB,
    const float* __restrict__ bias, const int* __restrict__ nyBuf,
    float* __restrict__ Cf, ushort* __restrict__ Chi, size_t zsC,
    int sdA, int sdB, int N, int T)
{
    __shared__ char ldsb[73728];   // 3 bufs x 24KB { A 8KB | B 16KB }

    // XCD-aware bijective block swizzle (grid totals divisible by 8)
    const int gx = gridDim.x, gxy = gx * gridDim.y;
    const int total = gxy * gridDim.z;
    int hsw = blockIdx.z * gxy + blockIdx.y * gx + blockIdx.x;
    hsw = (hsw & 7) * (total >> 3) + (hsw >> 3);
    const int z = hsw / gxy;
    const int rem = hsw - z * gxy;
    const int by = rem / gx;
    const int bx = rem - by * gx;

    int NY = 0, NYPAD = 0;
    if constexpr (MODE != 0) { NY = nyBuf[2 * z]; NYPAD = nyBuf[2 * z + 1]; }
    const int m0 = by * 128, n0 = bx * 256;
    if constexpr (MODE == 1) { if (m0 >= 2048 && m0 - 2048 >= NYPAD) return; }
    if constexpr (MODE == 2) { if (n0 >= NYPAD) return; }
    if constexpr (MODE == 3) { T = NYPAD >> 5; }

    const int tid = threadIdx.x;
    const int lane = tid & 63;
    const int wv = tid >> 6;
    const int wm = (wv >> 1) * 64;      // M half (0|64)
    const int wn = (wv & 1) * 128;      // N half (0|128)

    // staging (pair-row swizzle) per 4KB dest chunk (64 rows x 32 k):
    // logical slot s = (tid&7)^((tid>>3)&7); row = 2*(tid>>3)+(s>>2); k=(s&3)*8
    const int pl  = tid >> 3;
    const int ss  = (tid & 7) ^ (pl & 7);
    const int sr0 = 2 * pl + (ss >> 2);
    const int ske = (ss & 3) * 8;
    const int tb  = tid * 16;

    const ushort* gA0 = A + (size_t)z * zsA + (size_t)(m0 + sr0) * sdA + ske;
    const ushort* gA1 = gA0 + (size_t)64 * sdA;
    const ushort* gB0 = B + (size_t)z * zsB + (size_t)(n0 + sr0) * sdB + ske;
    const ushort* gB1 = gB0 + (size_t)64 * sdB;
    const ushort* gB2 = gB0 + (size_t)128 * sdB;
    const ushort* gB3 = gB0 + (size_t)192 * sdB;

    // compute-side read addresses (same swizzle)
    const int fr = lane & 15, fq = lane >> 4;
    const int sl = (((fr & 1) << 2) | fq) ^ ((fr >> 1) & 7);
    const int aoff = wm * 64 + (fr >> 1) * 128 + sl * 16;          // + i*1024
    const int boff = 8192 + wn * 64 + (fr >> 1) * 128 + sl * 16;   // + j*1024

    f32x4 acc[4][8];
    #pragma unroll
    for (int i = 0; i < 4; ++i)
        #pragma unroll
        for (int j = 0; j < 8; ++j)
            acc[i][j] = (f32x4){0.f, 0.f, 0.f, 0.f};

    // stage one 32-K tile (6 x ld16/thread = 24KB) at k-offset KO into buffer D
    auto stage = [&](int ko, int buf) {
        char* d = ldsb + buf * 24576;
        ld16(gA0 + ko, (ushort*)(d + tb));
        ld16(gA1 + ko, (ushort*)(d + 4096 + tb));
        ld16(gB0 + ko, (ushort*)(d + 8192 + tb));
        ld16(gB1 + ko, (ushort*)(d + 12288 + tb));
        ld16(gB2 + ko, (ushort*)(d + 16384 + tb));
        ld16(gB3 + ko, (ushort*)(d + 20480 + tb));
    };

    // prologue: tiles 0,1 in flight (12 loads/thread outstanding)
    stage(0, 0);
    stage(32, 1);

    int buf = 0;
    for (int t = 0; t < T; ++t) {
        if (t + 2 < T) {
            stage(64, buf == 0 ? 2 : (buf - 1));   // buf (t+2)%3
            VMW(12);                               // tile t landed; t+1,t+2 in flight
        } else if (t + 1 < T) {
            VMW(6);                                // tile t landed; t+1 in flight
        } else {
            VMW(0);                                // last tile landed
        }
        BAR();                                     // all waves: tile t resident

        {
            const char* pa = ldsb + buf * 24576 + aoff;
            const char* pb = ldsb + buf * 24576 + boff;
            f16x8 a[4], b[8];
            #pragma unroll
            for (int i = 0; i < 4; ++i) a[i] = *(const f16x8*)(pa + i * 1024);
            #pragma unroll
            for (int j = 0; j < 8; ++j) b[j] = *(const f16x8*)(pb + j * 1024);
            __builtin_amdgcn_s_setprio(1);
            #pragma unroll
            for (int i = 0; i < 4; ++i)
                #pragma unroll
                for (int j = 0; j < 8; ++j)
                    acc[i][j] = __builtin_amdgcn_mfma_f32_16x16x32_f16(a[i], b[j], acc[i][j], 0, 0, 0);
            __builtin_amdgcn_s_setprio(0);
        }
        BAR();                                     // reads done before buf reuse

        gA0 += 32; gA1 += 32; gB0 += 32; gB1 += 32; gB2 += 32; gB3 += 32;
        buf = (buf == 2) ? 0 : (buf + 1);
    }

    // epilogue: within 16x16 frag, col = fr, row = fq*4 + r
    #pragma unroll
    for (int j = 0; j < 8; ++j) {
        const int col = n0 + wn + j * 16 + fr;
        float bb = 0.f;
        if constexpr (EPI == 1) bb = bias[col];
        #pragma unroll
        for (int i = 0; i < 4; ++i) {
            const int row = m0 + wm + i * 16 + fq * 4;
            #pragma unroll
            for (int r = 0; r < 4; ++r) {
                const float v = acc[i][j][r];
                const size_t o = (size_t)z * zsC + (size_t)(row + r) * N + col;
                if constexpr (EPI == 0) {
                    Cf[o] = v;
                } else if constexpr (EPI == 1) {
                    Chi[o] = h2u((_Float16)fmaxf(v + bb, 0.f));
                } else {
                    Cf[o] = (col >= NY) ? -INFINITY : v;
                }
            }
        }
    }
}

// per batch: compact index list of unmasked cols + NY/NYPAD (ceil128, min 256)
__global__ __launch_bounds__(256) void build_idx(const int* __restrict__ mask,
    int* __restrict__ idx, int* __restrict__ nyBuf)
{
    const int z = blockIdx.x;
    const int* mb = mask + (size_t)z * 2048;
    __shared__ int part[256];
    const int tid = threadIdx.x;
    int keep[8]; int c = 0;
    #pragma unroll
    for (int k = 0; k < 8; ++k) { keep[k] = (mb[tid * 8 + k] == 0); c += keep[k]; }
    part[tid] = c;
    for (int off = 1; off < 256; off <<= 1) {
        __syncthreads();
        const int v = (tid >= off) ? part[tid - off] : 0;
        __syncthreads();
        part[tid] += v;
    }
    __syncthreads();
    int pos = part[tid] - c;   // exclusive prefix
    #pragma unroll
    for (int k = 0; k < 8; ++k)
        if (keep[k]) idx[(size_t)z * 2048 + (pos++)] = tid * 8 + k;
    if (tid == 255) {
        const int ny = part[255];
        int nyp = (ny + 127) & ~127;
        if (nyp < 256) nyp = 256;
        nyBuf[2 * z] = ny;
        nyBuf[2 * z + 1] = nyp;
    }
}

// broadcast NYMAX = max_z NYPAD into every z's NYPAD slot (uniform T)
__global__ __launch_bounds__(64) void reduce_ny(int* __restrict__ nyBuf)
{
    const int lane = threadIdx.x;
    int v = (lane < 16) ? nyBuf[2 * lane + 1] : 0;
    #pragma unroll
    for (int off = 8; off >= 1; off >>= 1)
        v = max(v, __shfl_xor(v, off));
    if (lane < 16) nyBuf[2 * lane + 1] = v;
}

// fp32 -> fp16, 4 elems/thread, z-batched (also used for W with grid.z=1)
__global__ __launch_bounds__(256) void cvt_f16(const float* __restrict__ in,
    ushort* __restrict__ o, size_t sIn4, size_t sOut)
{
    const size_t z = blockIdx.z;
    const int i = blockIdx.x * 256 + threadIdx.x;
    const float4 v = reinterpret_cast<const float4*>(in)[z * sIn4 + i];
    ushort4 h;
    h.x = h2u((_Float16)v.x); h.y = h2u((_Float16)v.y);
    h.z = h2u((_Float16)v.z); h.w = h2u((_Float16)v.w);
    reinterpret_cast<ushort4*>(o + z * sOut)[i] = h;
}

// gather compacted y rows -> fp16 rows + transpose (1024 x 2048); pad rows zero
__global__ __launch_bounds__(256) void gather_y(const float* __restrict__ y,
    const int* __restrict__ idx, const int* __restrict__ nyBuf,
    ushort* __restrict__ rH, ushort* __restrict__ tT,
    size_t sIn, size_t sR, size_t sT)
{
    __shared__ float tile[32][33];
    const size_t z = blockIdx.z;
    const int NY = nyBuf[2 * z], NYPAD = nyBuf[2 * z + 1];
    const int r0 = blockIdx.y * 32;
    if (r0 >= NYPAD) return;
    const int c0 = blockIdx.x * 32;
    const float* yb = y + z * sIn;
    const int* idxb = idx + z * 2048;
    const int tx = threadIdx.x & 31, ty = threadIdx.x >> 5;
    #pragma unroll
    for (int k = 0; k < 4; ++k) {
        const int i = r0 + ty + k * 8;
        float v = 0.f;
        if (i < NY) v = yb[(size_t)idxb[i] * 1024 + c0 + tx];
        tile[ty + k * 8][tx] = v;
        rH[z * sR + (size_t)i * 1024 + c0 + tx] = h2u((_Float16)v);
    }
    __syncthreads();
    #pragma unroll
    for (int k = 0; k < 4; ++k) {
        const int c = c0 + ty + k * 8;
        tT[z * sT + (size_t)c * 2048 + r0 + tx] = h2u((_Float16)tile[tx][ty + k * 8]);
    }
}

// row softmax over NYPAD cols -> fp16; grid.x = G*2048 rows
__global__ __launch_bounds__(256) void softmax_f16(const float* __restrict__ S,
    ushort* __restrict__ Wout, const int* __restrict__ nyBuf, size_t sS, size_t sW)
{
    const size_t row = blockIdx.x;
    const size_t b = row >> 11, r = row & 2047;
    const int nf4 = nyBuf[2 * b + 1] >> 2;   // NYPAD / 4
    const float4* p4 = reinterpret_cast<const float4*>(S + b * sS + r * 2048);
    ushort4* q4 = reinterpret_cast<ushort4*>(Wout + b * sW + r * 2048);
    const int tid = threadIdx.x;

    const float4 NEG = {-INFINITY, -INFINITY, -INFINITY, -INFINITY};
    float4 v0 = (tid < nf4) ? p4[tid] : NEG;
    float4 v1 = (tid + 256 < nf4) ? p4[tid + 256] : NEG;
    float m = fmaxf(fmaxf(fmaxf(v0.x, v0.y), fmaxf(v0.z, v0.w)),
                    fmaxf(fmaxf(v1.x, v1.y), fmaxf(v1.z, v1.w)));
    #pragma unroll
    for (int off = 32; off >= 1; off >>= 1)
        m = fmaxf(m, __shfl_xor(m, off));

    __shared__ float redm[4], reds[4];
    if ((tid & 63) == 0) redm[tid >> 6] = m;
    __syncthreads();
    m = fmaxf(fmaxf(redm[0], redm[1]), fmaxf(redm[2], redm[3]));

    float e[8];
    e[0] = __expf(v0.x - m); e[1] = __expf(v0.y - m);
    e[2] = __expf(v0.z - m); e[3] = __expf(v0.w - m);
    e[4] = __expf(v1.x - m); e[5] = __expf(v1.y - m);
    e[6] = __expf(v1.z - m); e[7] = __expf(v1.w - m);
    float s = ((e[0] + e[1]) + (e[2] + e[3])) + ((e[4] + e[5]) + (e[6] + e[7]));
    #pragma unroll
    for (int off = 32; off >= 1; off >>= 1)
        s += __shfl_xor(s, off);
    if ((tid & 63) == 0) reds[tid >> 6] = s;
    __syncthreads();
    s = reds[0] + reds[1] + reds[2] + reds[3];

    const float inv = 1.f / s;
    ushort4 o0, o1;
    o0.x = h2u((_Float16)(e[0] * inv)); o0.y = h2u((_Float16)(e[1] * inv));
    o0.z = h2u((_Float16)(e[2] * inv)); o0.w = h2u((_Float16)(e[3] * inv));
    o1.x = h2u((_Float16)(e[4] * inv)); o1.y = h2u((_Float16)(e[5] * inv));
    o1.z = h2u((_Float16)(e[6] * inv)); o1.w = h2u((_Float16)(e[7] * inv));
    if (tid < nf4) q4[tid] = o0;
    if (tid + 256 < nf4) q4[tid + 256] = o1;
}

extern "C" void kernel_launch(void* const* d_in, const int* in_sizes, int n_in,
                              void* d_out, int out_size, void* d_ws, size_t ws_size,
                              hipStream_t stream)
{
    const float* x    = (const float*)d_in[0];  // (16, 2048, 1024)
    const float* y    = (const float*)d_in[1];  // (16, 2048, 1024)
    const int* ymask  = (const int*)d_in[2];    // (16, 2048)
    const float* W    = (const float*)d_in[3];  // (1024, 1024)
    const float* bias = (const float*)d_in[4];  // (1024,)
    float* out = (float*)d_out;

    const size_t BD = 2097152;                  // 2048*1024

    // hdr 4MB: W16 2MB | idx 128KB | nyBuf
    // per batch: R1 16MB (xy fp16 8MB; sc fp32 aliases) | R2 8MB p/w | R3 4MB yTc
    const size_t perBatch = 29360128ull;
    int G = 16;
    while (G > 1 && 4194304ull + (size_t)G * perBatch > ws_size) G >>= 1;

    uint8_t* wsb = (uint8_t*)d_ws;
    ushort* W16  = (ushort*)wsb;                         // 2 MB
    int* idxBuf  = (int*)(wsb + 2097152);                // 128 KB
    int* nyBuf   = (int*)(wsb + 2097152 + 131072);       // 128 B
    uint8_t* r1  = wsb + 4194304;                        // G * 16MB
    uint8_t* r2  = r1 + (size_t)G * 16777216;            // G * 8MB
    uint8_t* r3  = r2 + (size_t)G * 8388608;             // G * 4MB

    ushort* xyHi = (ushort*)r1;        // z-stride 8388608 ush
    float*  sc   = (float*)r1;         // z-stride 4194304 f32
    ushort* pHi  = (ushort*)r2;        // z-stride 4194304 ush; w aliases
    ushort* yT   = (ushort*)r3;        // z-stride 2097152 ush (D x 2048 compact)

    cvt_f16<<<dim3(1024, 1, 1), dim3(256), 0, stream>>>(W, W16, 0, 0);
    build_idx<<<dim3(16), dim3(256), 0, stream>>>(ymask, idxBuf, nyBuf);
    reduce_ny<<<dim3(1), dim3(64), 0, stream>>>(nyBuf);

    for (int bs = 0; bs < 16; bs += G) {
        const float* xg = x + (size_t)bs * BD;
        const float* yg = y + (size_t)bs * BD;
        const int* nyB  = nyBuf + 2 * bs;

        // x -> xy rows [0,2048) fp16
        cvt_f16<<<dim3(2048, 1, G), dim3(256), 0, stream>>>(
            xg, xyHi, BD / 4, 8388608);
        // compacted y -> xy rows [2048, 2048+NYMAX) fp16 + yTc fp16
        gather_y<<<dim3(32, 64, G), dim3(256), 0, stream>>>(
            yg, idxBuf + (size_t)bs * 2048, nyB,
            xyHi + BD, yT, BD, 8388608, BD);

        // proj: M=2048+NYMAX (early exit; grid covers 4096), N=1024, K=1024 (T=32)
        gemmw<1, 1><<<dim3(4, 32, G), dim3(256), 0, stream>>>(
            xyHi, 8388608, W16, 0,
            bias, nyB,
            nullptr, pHi, 4194304, 1024, 1024, 1024, 32);

        // scores: M=2048, N=NYMAX (early exit; grid covers 2048), K=1024 (T=32)
        gemmw<2, 2><<<dim3(8, 16, G), dim3(256), 0, stream>>>(
            pHi, 4194304, pHi + BD, 4194304,
            nullptr, nyB,
            sc, nullptr, 4194304, 1024, 1024, 2048, 32);

        // softmax over NYMAX cols -> w (aliases pHi)
        softmax_f16<<<dim3(G * 2048), dim3(256), 0, stream>>>(
            sc, pHi, nyB, 4194304, 4194304);

        // out: M=2048, N=1024, K=NYMAX (uniform T = NYMAX/32)
        gemmw<0, 3><<<dim3(4, 16, G), dim3(256), 0, stream>>>(
            pHi, 4194304, yT, 2097152,
            nullptr, nyB,
            out + (size_t)bs * BD, nullptr, BD, 2048, 2048, 1024, 32);
    }
}

// Round 21
// 492.511 us; speedup vs baseline: 1.0492x; 1.0492x over previous
//
#include <hip/hip_runtime.h>
#include <math.h>
#include <stdint.h>

// B=16, XL=YL=2048, D=1024. fp16 1-pass pipeline + mask compaction (per-z NYPAD,
// ceil128 — NYMAX broadcast reverted, R20: -4.6%):
//   build_idx: compact unmasked y col indices; NY, NYPAD
//   cvt_f16  : x -> fp16 rows [0,2048)
//   gather_y : yc rows fp16 (rows [2048,2048+NYPAD)) + yT (D x NYPAD) fp16
//   proj     : p = relu([x;yc]16 @ W16^T + b) -> pHi fp16   (gemm128 EPI1)
//   score    : sc = xp @ ypc^T, col>=NY -> -inf -> fp32     (gemm128 EPI2)
//   soft     : w = softmax over NYPAD cols -> fp16 (aliases pHi)
//   out      : out = w @ yT^T, K=NYPAD (runtime T) -> fp32  (gemm128 EPI0)
// gemm128 (R17-mechanism x 3-block TLP): 128x128 tile, 4 waves (wave 64x64,
// acc 4x4 = 64 VGPR -> ~100 total, no spill), BK=32, TRIPLE-buffered LDS
// (3 x 16KB = 48KB -> 3 blocks/CU by LDS; plain launch_bounds(256), no
// min-waves clamp — R18's (256,3) clamp spilled a 128-VGPR acc). Counted
// vmcnt never drains mid-loop: stage(t+2) then vmcnt(8) keeps 2 tiles
// (8 loads/thread) in flight across both barriers; tail 4 -> 0. setprio(1)
// around MFMA cluster. Pair-row XOR swizzle (measured 0-conflict) +
// XCD-bijective block swizzle.

typedef __attribute__((ext_vector_type(8))) _Float16 f16x8;
typedef __attribute__((ext_vector_type(4))) float f32x4;

__device__ __forceinline__ ushort h2u(_Float16 h) { return __builtin_bit_cast(ushort, h); }

__device__ __forceinline__ void ld16(const ushort* g, ushort* l) {
    __builtin_amdgcn_global_load_lds(
        (__attribute__((address_space(1))) void*)(g),
        (__attribute__((address_space(3))) void*)(l), 16, 0, 0);
}

#define BAR()   { __builtin_amdgcn_s_barrier(); asm volatile("" ::: "memory"); }
#define VMW(N)  asm volatile("s_waitcnt vmcnt(" #N ")" ::: "memory");

// C = A @ B^T; A,B fp16 k-contiguous. Tile 128x128, BK=32, K = T*32.
// MODE 1: proj (A-row early exit >= 2048+NYPAD). MODE 2: scores (B-col exit
// >= NYPAD; col>=NY -> -inf). MODE 3: out (runtime T = NYPAD/32).
// EPI 0: fp32 C. EPI 1: relu(C+bias[n]) -> fp16 Chi. EPI 2: -inf mask, fp32.
template<int EPI, int MODE>
__global__ __launch_bounds__(256) void gemm128(
    const ushort* __restrict__ A, size_t zsA,
    const ushort* __restrict__ B, size_t zsB,
    const float* __restrict__ bias, const int* __restrict__ nyBuf,
    float* __restrict__ Cf, ushort* __restrict__ Chi, size_t zsC,
    int sdA, int sdB, int N, int T)
{
    __shared__ char ldsb[49152];   // 3 bufs x 16KB { A 8KB | B 8KB }

    // XCD-aware bijective block swizzle (grid totals divisible by 8)
    const int gx = gridDim.x, gxy = gx * gridDim.y;
    const int total = gxy * gridDim.z;
    int hsw = blockIdx.z * gxy + blockIdx.y * gx + blockIdx.x;
    hsw = (hsw & 7) * (total >> 3) + (hsw >> 3);
    const int z = hsw / gxy;
    const int rem = hsw - z * gxy;
    const int by = rem / gx;
    const int bx = rem - by * gx;

    int NY = 0, NYPAD = 0;
    if constexpr (MODE != 0) { NY = nyBuf[2 * z]; NYPAD = nyBuf[2 * z + 1]; }
    const int m0 = by * 128, n0 = bx * 128;
    if constexpr (MODE == 1) { if (m0 >= 2048 && m0 - 2048 >= NYPAD) return; }
    if constexpr (MODE == 2) { if (n0 >= NYPAD) return; }
    if constexpr (MODE == 3) { T = NYPAD >> 5; }

    const int tid = threadIdx.x;
    const int lane = tid & 63;
    const int wv = tid >> 6;
    const int wm = (wv >> 1) * 64, wn = (wv & 1) * 64;

    // staging (pair-row swizzle) per 4KB dest chunk (64 rows x 32 k):
    // logical slot s = (tid&7)^((tid>>3)&7); row = 2*(tid>>3)+(s>>2); k=(s&3)*8
    const int pl  = tid >> 3;
    const int ss  = (tid & 7) ^ (pl & 7);
    const int sr0 = 2 * pl + (ss >> 2);
    const int ske = (ss & 3) * 8;
    const int tb  = tid * 16;

    const ushort* gA0 = A + (size_t)z * zsA + (size_t)(m0 + sr0) * sdA + ske;
    const ushort* gA1 = gA0 + (size_t)64 * sdA;
    const ushort* gB0 = B + (size_t)z * zsB + (size_t)(n0 + sr0) * sdB + ske;
    const ushort* gB1 = gB0 + (size_t)64 * sdB;

    // compute-side read addresses (same swizzle)
    const int fr = lane & 15, fq = lane >> 4;
    const int sl = (((fr & 1) << 2) | fq) ^ ((fr >> 1) & 7);
    const int aoff = wm * 64 + (fr >> 1) * 128 + sl * 16;          // + i*1024
    const int boff = 8192 + wn * 64 + (fr >> 1) * 128 + sl * 16;   // + j*1024

    f32x4 acc[4][4];
    #pragma unroll
    for (int i = 0; i < 4; ++i)
        #pragma unroll
        for (int j = 0; j < 4; ++j)
            acc[i][j] = (f32x4){0.f, 0.f, 0.f, 0.f};

    // stage one 32-K tile (4 x ld16/thread = 16KB) at k-offset KO into buffer D
    auto stage = [&](int ko, int buf) {
        char* d = ldsb + buf * 16384;
        ld16(gA0 + ko, (ushort*)(d + tb));
        ld16(gA1 + ko, (ushort*)(d + 4096 + tb));
        ld16(gB0 + ko, (ushort*)(d + 8192 + tb));
        ld16(gB1 + ko, (ushort*)(d + 12288 + tb));
    };

    // prologue: tiles 0,1 in flight (8 loads/thread outstanding)
    stage(0, 0);
    stage(32, 1);

    int buf = 0;
    for (int t = 0; t < T; ++t) {
        if (t + 2 < T) {
            stage(64, buf == 0 ? 2 : (buf - 1));   // buf (t+2)%3
            VMW(8);                                // tile t landed; t+1,t+2 in flight
        } else if (t + 1 < T) {
            VMW(4);                                // tile t landed; t+1 in flight
        } else {
            VMW(0);                                // last tile landed
        }
        BAR();                                     // all waves: tile t resident

        {
            const char* pa = ldsb + buf * 16384 + aoff;
            const char* pb = ldsb + buf * 16384 + boff;
            f16x8 a[4], b[4];
            #pragma unroll
            for (int i = 0; i < 4; ++i) a[i] = *(const f16x8*)(pa + i * 1024);
            #pragma unroll
            for (int j = 0; j < 4; ++j) b[j] = *(const f16x8*)(pb + j * 1024);
            __builtin_amdgcn_s_setprio(1);
            #pragma unroll
            for (int i = 0; i < 4; ++i)
                #pragma unroll
                for (int j = 0; j < 4; ++j)
                    acc[i][j] = __builtin_amdgcn_mfma_f32_16x16x32_f16(a[i], b[j], acc[i][j], 0, 0, 0);
            __builtin_amdgcn_s_setprio(0);
        }
        BAR();                                     // reads done before buf reuse

        gA0 += 32; gA1 += 32; gB0 += 32; gB1 += 32;
        buf = (buf == 2) ? 0 : (buf + 1);
    }

    // epilogue: within 16x16 frag, col = fr, row = fq*4 + r
    #pragma unroll
    for (int j = 0; j < 4; ++j) {
        const int col = n0 + wn + j * 16 + fr;
        float bb = 0.f;
        if constexpr (EPI == 1) bb = bias[col];
        #pragma unroll
        for (int i = 0; i < 4; ++i) {
            const int row = m0 + wm + i * 16 + fq * 4;
            #pragma unroll
            for (int r = 0; r < 4; ++r) {
                const float v = acc[i][j][r];
                const size_t o = (size_t)z * zsC + (size_t)(row + r) * N + col;
                if constexpr (EPI == 0) {
                    Cf[o] = v;
                } else if constexpr (EPI == 1) {
                    Chi[o] = h2u((_Float16)fmaxf(v + bb, 0.f));
                } else {
                    Cf[o] = (col >= NY) ? -INFINITY : v;
                }
            }
        }
    }
}

// per batch: compact index list of unmasked cols + NY/NYPAD (ceil128, min 256)
__global__ __launch_bounds__(256) void build_idx(const int* __restrict__ mask,
    int* __restrict__ idx, int* __restrict__ nyBuf)
{
    const int z = blockIdx.x;
    const int* mb = mask + (size_t)z * 2048;
    __shared__ int part[256];
    const int tid = threadIdx.x;
    int keep[8]; int c = 0;
    #pragma unroll
    for (int k = 0; k < 8; ++k) { keep[k] = (mb[tid * 8 + k] == 0); c += keep[k]; }
    part[tid] = c;
    for (int off = 1; off < 256; off <<= 1) {
        __syncthreads();
        const int v = (tid >= off) ? part[tid - off] : 0;
        __syncthreads();
        part[tid] += v;
    }
    __syncthreads();
    int pos = part[tid] - c;   // exclusive prefix
    #pragma unroll
    for (int k = 0; k < 8; ++k)
        if (keep[k]) idx[(size_t)z * 2048 + (pos++)] = tid * 8 + k;
    if (tid == 255) {
        const int ny = part[255];
        int nyp = (ny + 127) & ~127;
        if (nyp < 256) nyp = 256;
        nyBuf[2 * z] = ny;
        nyBuf[2 * z + 1] = nyp;
    }
}

// fp32 -> fp16, 4 elems/thread, z-batched (also used for W with grid.z=1)
__global__ __launch_bounds__(256) void cvt_f16(const float* __restrict__ in,
    ushort* __restrict__ o, size_t sIn4, size_t sOut)
{
    const size_t z = blockIdx.z;
    const int i = blockIdx.x * 256 + threadIdx.x;
    const float4 v = reinterpret_cast<const float4*>(in)[z * sIn4 + i];
    ushort4 h;
    h.x = h2u((_Float16)v.x); h.y = h2u((_Float16)v.y);
    h.z = h2u((_Float16)v.z); h.w = h2u((_Float16)v.w);
    reinterpret_cast<ushort4*>(o + z * sOut)[i] = h;
}

// gather compacted y rows -> fp16 rows + transpose (1024 x 2048); pad rows zero
__global__ __launch_bounds__(256) void gather_y(const float* __restrict__ y,
    const int* __restrict__ idx, const int* __restrict__ nyBuf,
    ushort* __restrict__ rH, ushort* __restrict__ tT,
    size_t sIn, size_t sR, size_t sT)
{
    __shared__ float tile[32][33];
    const size_t z = blockIdx.z;
    const int NY = nyBuf[2 * z], NYPAD = nyBuf[2 * z + 1];
    const int r0 = blockIdx.y * 32;
    if (r0 >= NYPAD) return;
    const int c0 = blockIdx.x * 32;
    const float* yb = y + z * sIn;
    const int* idxb = idx + z * 2048;
    const int tx = threadIdx.x & 31, ty = threadIdx.x >> 5;
    #pragma unroll
    for (int k = 0; k < 4; ++k) {
        const int i = r0 + ty + k * 8;
        float v = 0.f;
        if (i < NY) v = yb[(size_t)idxb[i] * 1024 + c0 + tx];
        tile[ty + k * 8][tx] = v;
        rH[z * sR + (size_t)i * 1024 + c0 + tx] = h2u((_Float16)v);
    }
    __syncthreads();
    #pragma unroll
    for (int k = 0; k < 4; ++k) {
        const int c = c0 + ty + k * 8;
        tT[z * sT + (size_t)c * 2048 + r0 + tx] = h2u((_Float16)tile[tx][ty + k * 8]);
    }
}

// row softmax over NYPAD cols -> fp16; grid.x = G*2048 rows
__global__ __launch_bounds__(256) void softmax_f16(const float* __restrict__ S,
    ushort* __restrict__ Wout, const int* __restrict__ nyBuf, size_t sS, size_t sW)
{
    const size_t row = blockIdx.x;
    const size_t b = row >> 11, r = row & 2047;
    const int nf4 = nyBuf[2 * b + 1] >> 2;   // NYPAD / 4
    const float4* p4 = reinterpret_cast<const float4*>(S + b * sS + r * 2048);
    ushort4* q4 = reinterpret_cast<ushort4*>(Wout + b * sW + r * 2048);
    const int tid = threadIdx.x;

    const float4 NEG = {-INFINITY, -INFINITY, -INFINITY, -INFINITY};
    float4 v0 = (tid < nf4) ? p4[tid] : NEG;
    float4 v1 = (tid + 256 < nf4) ? p4[tid + 256] : NEG;
    float m = fmaxf(fmaxf(fmaxf(v0.x, v0.y), fmaxf(v0.z, v0.w)),
                    fmaxf(fmaxf(v1.x, v1.y), fmaxf(v1.z, v1.w)));
    #pragma unroll
    for (int off = 32; off >= 1; off >>= 1)
        m = fmaxf(m, __shfl_xor(m, off));

    __shared__ float redm[4], reds[4];
    if ((tid & 63) == 0) redm[tid >> 6] = m;
    __syncthreads();
    m = fmaxf(fmaxf(redm[0], redm[1]), fmaxf(redm[2], redm[3]));

    float e[8];
    e[0] = __expf(v0.x - m); e[1] = __expf(v0.y - m);
    e[2] = __expf(v0.z - m); e[3] = __expf(v0.w - m);
    e[4] = __expf(v1.x - m); e[5] = __expf(v1.y - m);
    e[6] = __expf(v1.z - m); e[7] = __expf(v1.w - m);
    float s = ((e[0] + e[1]) + (e[2] + e[3])) + ((e[4] + e[5]) + (e[6] + e[7]));
    #pragma unroll
    for (int off = 32; off >= 1; off >>= 1)
        s += __shfl_xor(s, off);
    if ((tid & 63) == 0) reds[tid >> 6] = s;
    __syncthreads();
    s = reds[0] + reds[1] + reds[2] + reds[3];

    const float inv = 1.f / s;
    ushort4 o0, o1;
    o0.x = h2u((_Float16)(e[0] * inv)); o0.y = h2u((_Float16)(e[1] * inv));
    o0.z = h2u((_Float16)(e[2] * inv)); o0.w = h2u((_Float16)(e[3] * inv));
    o1.x = h2u((_Float16)(e[4] * inv)); o1.y = h2u((_Float16)(e[5] * inv));
    o1.z = h2u((_Float16)(e[6] * inv)); o1.w = h2u((_Float16)(e[7] * inv));
    if (tid < nf4) q4[tid] = o0;
    if (tid + 256 < nf4) q4[tid + 256] = o1;
}

extern "C" void kernel_launch(void* const* d_in, const int* in_sizes, int n_in,
                              void* d_out, int out_size, void* d_ws, size_t ws_size,
                              hipStream_t stream)
{
    const float* x    = (const float*)d_in[0];  // (16, 2048, 1024)
    const float* y    = (const float*)d_in[1];  // (16, 2048, 1024)
    const int* ymask  = (const int*)d_in[2];    // (16, 2048)
    const float* W    = (const float*)d_in[3];  // (1024, 1024)
    const float* bias = (const float*)d_in[4];  // (1024,)
    float* out = (float*)d_out;

    const size_t BD = 2097152;                  // 2048*1024

    // hdr 4MB: W16 2MB | idx 128KB | nyBuf
    // per batch: R1 16MB (xy fp16 8MB; sc fp32 aliases) | R2 8MB p/w | R3 4MB yTc
    const size_t perBatch = 29360128ull;
    int G = 16;
    while (G > 1 && 4194304ull + (size_t)G * perBatch > ws_size) G >>= 1;

    uint8_t* wsb = (uint8_t*)d_ws;
    ushort* W16  = (ushort*)wsb;                         // 2 MB
    int* idxBuf  = (int*)(wsb + 2097152);                // 128 KB
    int* nyBuf   = (int*)(wsb + 2097152 + 131072);       // 128 B
    uint8_t* r1  = wsb + 4194304;                        // G * 16MB
    uint8_t* r2  = r1 + (size_t)G * 16777216;            // G * 8MB
    uint8_t* r3  = r2 + (size_t)G * 8388608;             // G * 4MB

    ushort* xyHi = (ushort*)r1;        // z-stride 8388608 ush
    float*  sc   = (float*)r1;         // z-stride 4194304 f32
    ushort* pHi  = (ushort*)r2;        // z-stride 4194304 ush; w aliases
    ushort* yT   = (ushort*)r3;        // z-stride 2097152 ush (D x 2048 compact)

    cvt_f16<<<dim3(1024, 1, 1), dim3(256), 0, stream>>>(W, W16, 0, 0);
    build_idx<<<dim3(16), dim3(256), 0, stream>>>(ymask, idxBuf, nyBuf);

    for (int bs = 0; bs < 16; bs += G) {
        const float* xg = x + (size_t)bs * BD;
        const float* yg = y + (size_t)bs * BD;
        const int* nyB  = nyBuf + 2 * bs;

        // x -> xy rows [0,2048) fp16
        cvt_f16<<<dim3(2048, 1, G), dim3(256), 0, stream>>>(
            xg, xyHi, BD / 4, 8388608);
        // compacted y -> xy rows [2048, 2048+NYPAD) fp16 + yTc fp16
        gather_y<<<dim3(32, 64, G), dim3(256), 0, stream>>>(
            yg, idxBuf + (size_t)bs * 2048, nyB,
            xyHi + BD, yT, BD, 8388608, BD);

        // proj: M=2048+NYPAD (early exit; grid covers 4096), N=1024, K=1024 (T=32)
        gemm128<1, 1><<<dim3(8, 32, G), dim3(256), 0, stream>>>(
            xyHi, 8388608, W16, 0,
            bias, nyB,
            nullptr, pHi, 4194304, 1024, 1024, 1024, 32);

        // scores: M=2048, N=NYPAD (early exit; grid covers 2048), K=1024 (T=32)
        gemm128<2, 2><<<dim3(16, 16, G), dim3(256), 0, stream>>>(
            pHi, 4194304, pHi + BD, 4194304,
            nullptr, nyB,
            sc, nullptr, 4194304, 1024, 1024, 2048, 32);

        // softmax over NYPAD cols -> w (aliases pHi)
        softmax_f16<<<dim3(G * 2048), dim3(256), 0, stream>>>(
            sc, pHi, nyB, 4194304, 4194304);

        // out: M=2048, N=1024, K=NYPAD (runtime T = NYPAD/32)
        gemm128<0, 3><<<dim3(8, 16, G), dim3(256), 0, stream>>>(
            pHi, 4194304, yT, 2097152,
            nullptr, nyB,
            out + (size_t)bs * BD, nullptr, BD, 2048, 2048, 1024, 32);
    }
}